// Round 12
// baseline (179.099 us; speedup 1.0000x reference)
//
#include <hip/hip_runtime.h>
#include <hip/hip_cooperative_groups.h>
#include <math.h>

namespace cg = cooperative_groups;

#define NN 2048
#define BB 64
#define DD 512
#define NSEL 512  // NN/4

typedef float fx4 __attribute__((ext_vector_type(4)));

__device__ __forceinline__ void insert5b(float v, float t[5]) {
  float a = v, m;
  m = fmaxf(t[0], a); a = fminf(t[0], a); t[0] = m;
  m = fmaxf(t[1], a); a = fminf(t[1], a); t[1] = m;
  m = fmaxf(t[2], a); a = fminf(t[2], a); t[2] = m;
  m = fmaxf(t[3], a); a = fminf(t[3], a); t[3] = m;
  t[4] = fmaxf(t[4], a);
}

// ---------------------------------------------------------------------------
// Cooperative chain kernel: 129 blocks x 256 threads (trivially co-resident).
// P1: blocks 0..127 (wave 0): thr for row bk -> thr_g. grid.sync.
// P2: blocks 0..31: R10-shaped mkey (64 cols/block, thr staged in LDS):
//     key = #(att[:,c]>=thrA)+#(aoff[:,c]>=thrO) == 2*M. grid.sync.
// P3: block 0: fully-parallel stable descending counting sort (R11 port,
//     validated) -> top_m + tail(f32). Matches jnp.argsort(-M) stable.
// ---------------------------------------------------------------------------
__global__ void __launch_bounds__(256)
chain_kernel(const float* __restrict__ att,
             const float* __restrict__ aoff,
             float* __restrict__ thr_g,
             int* __restrict__ key_g,
             int* __restrict__ top_m,
             float* __restrict__ out_tail) {
  __shared__ float sh_thr[128];
  __shared__ int chist[32][132];
  __shared__ int htot[132];
  __shared__ int gbase[132];
  cg::grid_group grid = cg::this_grid();
  int bk = blockIdx.x;
  int t  = threadIdx.x;
  int w = t >> 6, lane = t & 63;

  // ---- Phase 1: thresholds ----
  if (bk < 128 && w == 0) {
    const float* src = (bk < BB) ? att : aoff;
    int row = (bk < BB) ? bk : bk - BB;
    float tt[5] = {-INFINITY, -INFINITY, -INFINITY, -INFINITY, -INFINITY};
    const fx4* rp4 = (const fx4*)(src + (size_t)row * NN);
    #pragma unroll
    for (int k = 0; k < NN / 256; ++k) {
      fx4 v = rp4[lane + 64 * k];
      insert5b(v.x, tt); insert5b(v.y, tt); insert5b(v.z, tt); insert5b(v.w, tt);
    }
    for (int off = 1; off < 64; off <<= 1) {
      float bb[5];
      #pragma unroll
      for (int k = 0; k < 5; ++k) bb[k] = __shfl_xor(tt[k], off, 64);
      float m[5];
      int ia = 0, ib = 0;
      #pragma unroll
      for (int k = 0; k < 5; ++k) {
        float av = tt[ia], bv = bb[ib];
        bool ta = (av >= bv);
        m[k] = ta ? av : bv;
        ia += ta ? 1 : 0;
        ib += ta ? 0 : 1;
      }
      #pragma unroll
      for (int k = 0; k < 5; ++k) tt[k] = m[k];
    }
    if (lane == 0) thr_g[bk] = tt[4];
  }
  __threadfence();
  grid.sync();

  // ---- Phase 2: keys (blocks 0..31, R10 mkey shape) ----
  if (bk < 32) {
    if (t < 128) sh_thr[t] = thr_g[t];
    __syncthreads();
    if (t < 64) {
      int n = bk * 64 + t;
      int c = 0;
      #pragma unroll 16
      for (int b = 0; b < BB; ++b) c += (att[(size_t)b * NN + n] >= sh_thr[b]) ? 1 : 0;
      #pragma unroll 16
      for (int b = 0; b < BB; ++b) c += (aoff[(size_t)b * NN + n] >= sh_thr[BB + b]) ? 1 : 0;
      key_g[n] = c;
    }
  }
  __threadfence();
  grid.sync();

  // ---- Phase 3: sort (block 0; R11-validated 256-thread port) ----
  if (bk == 0) {
    for (int i = t; i < 32 * 132; i += 256) (&chist[0][0])[i] = 0;
    __syncthreads();

    unsigned long long lt = (lane == 0) ? 0ull : (~0ull >> (64 - lane));
    int kk[8];
    int pre[8];
    #pragma unroll
    for (int p = 0; p < 8; ++p) {
      int c = w * 8 + p;
      int n = c * 64 + lane;
      int k = key_g[n];
      kk[p] = k;
      atomicAdd(&chist[c][k], 1);
      unsigned long long m = ~0ull;
      #pragma unroll
      for (int bit = 0; bit < 8; ++bit) {
        unsigned long long bb = __ballot(((k >> bit) & 1) != 0);
        m &= ((k >> bit) & 1) ? bb : ~bb;
      }
      pre[p] = __popcll(m & lt);
    }
    __syncthreads();

    {
      int c = lane & 31;
      #pragma unroll
      for (int rd = 0; rd < 17; ++rd) {
        int kb = rd * 8 + w * 2 + (lane >> 5);
        if (kb <= 128) {
          int v = chist[c][kb];
          int inc = v;
          #pragma unroll
          for (int d = 1; d < 32; d <<= 1) {
            int o = __shfl_up(inc, d, 32);
            if (c >= d) inc += o;
          }
          chist[c][kb] = inc - v;
          if (c == 31) htot[kb] = inc;
        }
      }
    }
    __syncthreads();

    if (t < 64) {
      int carry = 0;
      #pragma unroll
      for (int rd = 0; rd < 3; ++rd) {
        int k = 128 - (rd * 64 + lane);
        int v = (k >= 0) ? htot[k] : 0;
        int inc = v;
        #pragma unroll
        for (int d = 1; d < 64; d <<= 1) {
          int o = __shfl_up(inc, d, 64);
          if (lane >= d) inc += o;
        }
        if (k >= 0) gbase[k] = carry + inc - v;
        carry += __shfl(inc, 63, 64);
      }
    }
    __syncthreads();

    #pragma unroll
    for (int p = 0; p < 8; ++p) {
      int c = w * 8 + p;
      int n = c * 64 + lane;
      int k = kk[p];
      int r = gbase[k] + chist[c][k] + pre[p];
      if (r < NSEL) { top_m[r] = n; out_tail[r] = (float)n; }
    }
  }
}

// ---------------------------------------------------------------------------
// Gather: R10 body, byte-identical.
// ---------------------------------------------------------------------------
__global__ void __launch_bounds__(256)
gather_kernel(const float* __restrict__ x,
              const float* __restrict__ y,
              const int* __restrict__ top_m,
              float* __restrict__ xs,
              float* __restrict__ ys) {
  __shared__ float rowbuf[4][NN];   // 32KB: one 8KB row per wave
  __shared__ int cols[NSEL];
  int t = threadIdx.x;
  int w = t >> 6, lane = t & 63;
  int blk = blockIdx.x;             // 0..1023
  int b = blk >> 4;
  int iblk = blk & 15;

  cols[t]       = top_m[t];
  cols[t + 256] = top_m[t + 256];
  __syncthreads();                  // the only block barrier

  float* myrow = rowbuf[w];
  int i0 = iblk * 32 + w * 8;       // this wave's 8 rows
  const float* ybase = y + (size_t)b * NN * NN;

  fx4 pr[8];
  {
    int r = cols[i0];
    const fx4* src = (const fx4*)(ybase + (size_t)r * NN);
    #pragma unroll
    for (int j = 0; j < 8; ++j)
      pr[j] = __builtin_nontemporal_load(&src[lane + 64 * j]);
  }

  #pragma unroll
  for (int k = 0; k < 8; ++k) {
    int i = i0 + k;
    {
      fx4* mb = (fx4*)myrow;
      #pragma unroll
      for (int j = 0; j < 8; ++j) mb[lane + 64 * j] = pr[j];
    }
    if (k < 7) {
      int rn = cols[i + 1];
      const fx4* src = (const fx4*)(ybase + (size_t)rn * NN);
      #pragma unroll
      for (int j = 0; j < 8; ++j)
        pr[j] = __builtin_nontemporal_load(&src[lane + 64 * j]);
    }
    {
      int r = cols[i];
      const fx4* xsrc = (const fx4*)(x + ((size_t)b * NN + r) * DD);
      fx4*       xdst = (fx4*)(xs + ((size_t)b * NSEL + i) * DD);
      #pragma unroll
      for (int j = 0; j < 2; ++j) {
        fx4 v = __builtin_nontemporal_load(&xsrc[lane + 64 * j]);
        __builtin_nontemporal_store(v, &xdst[lane + 64 * j]);
      }
    }
    {
      float o[8];
      #pragma unroll
      for (int j = 0; j < 8; ++j) o[j] = myrow[cols[8 * lane + j]];
      fx4* dst = (fx4*)(ys + ((size_t)b * NSEL + i) * DD);
      fx4 o0 = {o[0], o[1], o[2], o[3]};
      fx4 o1 = {o[4], o[5], o[6], o[7]};
      __builtin_nontemporal_store(o0, &dst[2 * lane]);
      __builtin_nontemporal_store(o1, &dst[2 * lane + 1]);
    }
  }
}

// ---------------------------------------------------------------------------
extern "C" void kernel_launch(void* const* d_in, const int* in_sizes, int n_in,
                              void* d_out, int out_size, void* d_ws, size_t ws_size,
                              hipStream_t stream) {
  const float* x    = (const float*)d_in[0];   // (64, 2048, 512)
  const float* y    = (const float*)d_in[1];   // (64, 2048, 2048)
  const float* att  = (const float*)d_in[2];   // (64, 2048)
  const float* aoff = (const float*)d_in[3];   // (64, 2048)

  float* out  = (float*)d_out;
  float* xs   = out;                                    // 64*512*512
  float* ysel = out + (size_t)BB * NSEL * DD;           // 64*512*512
  float* tail = ysel + (size_t)BB * NSEL * NSEL;        // 512 floats

  float* thr_g = (float*)d_ws;                          // 128 floats
  int*   key_g = (int*)d_ws + 128;                      // 2048 ints
  int*   top_m = (int*)d_ws + 128 + NN;                 // 512 ints

  void* args[] = { (void*)&att, (void*)&aoff, (void*)&thr_g,
                   (void*)&key_g, (void*)&top_m, (void*)&tail };
  hipLaunchCooperativeKernel((void*)chain_kernel, dim3(129), dim3(256),
                             args, 0, stream);
  hipLaunchKernelGGL(gather_kernel, dim3(BB * 16), dim3(256), 0, stream,
                     x, y, top_m, xs, ysel);
}

// Round 13
// 121.712 us; speedup vs baseline: 1.4715x; 1.4715x over previous
//
#include <hip/hip_runtime.h>
#include <math.h>

#define NN 2048
#define BB 64
#define DD 512
#define NSEL 512  // NN/4

typedef float fx4 __attribute__((ext_vector_type(4)));

// ---------------------------------------------------------------------------
// Kernel 1: per-row 5th-largest (thr). One wave per row. Branchless
// min/max insertion network (no divergence), fx4 vector loads.
// ---------------------------------------------------------------------------
__device__ __forceinline__ void insert5b(float v, float t[5]) {
  float a = v, m;
  m = fmaxf(t[0], a); a = fminf(t[0], a); t[0] = m;
  m = fmaxf(t[1], a); a = fminf(t[1], a); t[1] = m;
  m = fmaxf(t[2], a); a = fminf(t[2], a); t[2] = m;
  m = fmaxf(t[3], a); a = fminf(t[3], a); t[3] = m;
  t[4] = fmaxf(t[4], a);
}

__global__ void thr_kernel(const float* __restrict__ att,
                           const float* __restrict__ aoff,
                           float* __restrict__ thr) {
  int blk  = blockIdx.x;                 // 0..127
  const float* src = (blk < BB) ? att : aoff;
  int row  = (blk < BB) ? blk : blk - BB;
  int lane = threadIdx.x;                // 0..63

  float t[5] = {-INFINITY, -INFINITY, -INFINITY, -INFINITY, -INFINITY};
  const fx4* rp4 = (const fx4*)(src + (size_t)row * NN);
  #pragma unroll
  for (int k = 0; k < NN / 256; ++k) {   // 8 fx4 loads per lane
    fx4 v = rp4[lane + 64 * k];
    insert5b(v.x, t); insert5b(v.y, t); insert5b(v.z, t); insert5b(v.w, t);
  }

  // Butterfly merge of sorted-descending 5-lists across the 64-lane wave.
  for (int off = 1; off < 64; off <<= 1) {
    float b[5];
    #pragma unroll
    for (int k = 0; k < 5; ++k) b[k] = __shfl_xor(t[k], off, 64);
    float m[5];
    int ia = 0, ib = 0;
    #pragma unroll
    for (int k = 0; k < 5; ++k) {
      float av = t[ia], bv = b[ib];
      bool ta = (av >= bv);
      m[k] = ta ? av : bv;
      ia += ta ? 1 : 0;
      ib += ta ? 0 : 1;
    }
    #pragma unroll
    for (int k = 0; k < 5; ++k) t[k] = m[k];
  }
  if (lane == 0) thr[blk] = t[4];        // 5th largest (vals[:, PS])
}

// ---------------------------------------------------------------------------
// Kernel 2: key[n] = #(att[:,n] >= thr_att) + #(aoff[:,n] >= thr_off) == 2*M.
// ---------------------------------------------------------------------------
__global__ void mkey_kernel(const float* __restrict__ att,
                            const float* __restrict__ aoff,
                            const float* __restrict__ thr,
                            int* __restrict__ key) {
  int n = blockIdx.x * 64 + threadIdx.x;
  if (n >= NN) return;
  int c = 0;
  #pragma unroll 16
  for (int b = 0; b < BB; ++b) c += (att[(size_t)b * NN + n] >= thr[b]) ? 1 : 0;
  #pragma unroll 16
  for (int b = 0; b < BB; ++b) c += (aoff[(size_t)b * NN + n] >= thr[BB + b]) ? 1 : 0;
  key[n] = c;
}

// ---------------------------------------------------------------------------
// Kernel 3: stable descending counting-sort, fully parallel primitives.
//   rank(n) = gbase[k] + chunkpre[c][k] + in-chunk-pre(n)
// in-chunk prefix: wave-aligned chunks -> 8-ballot match mask + popcount.
// chunk prefix:    shfl_up segmented scan. gbase: one-wave suffix scan.
// Matches jnp.argsort(-M) stable semantics exactly.
// ---------------------------------------------------------------------------
__global__ void __launch_bounds__(1024)
topm_kernel(const int* __restrict__ key,
            int* __restrict__ top_m,
            float* __restrict__ out_tail) {
  __shared__ int chist[32][132];   // [chunk][bucket] -> exclusive prefix
  __shared__ int htot[132];
  __shared__ int gbase[132];
  int t = threadIdx.x;             // 0..1023
  int w = t >> 6, lane = t & 63;

  for (int i = t; i < 32 * 132; i += 1024) (&chist[0][0])[i] = 0;
  __syncthreads();

  int k0 = key[t];                 // element n0 = t       (chunk w)
  int k1 = key[t + 1024];          // element n1 = t+1024  (chunk 16+w)
  atomicAdd(&chist[w][k0], 1);
  atomicAdd(&chist[16 + w][k1], 1);
  __syncthreads();

  // chunk-exclusive prefix per bucket + bucket totals (segmented shfl scan)
  {
    int c = lane & 31;             // chunk within segment
    #pragma unroll
    for (int rd = 0; rd < 5; ++rd) {
      int kb = rd * 32 + w * 2 + (lane >> 5);
      if (kb <= 128) {
        int v = chist[c][kb];
        int inc = v;
        #pragma unroll
        for (int d = 1; d < 32; d <<= 1) {
          int o = __shfl_up(inc, d, 32);
          if (c >= d) inc += o;
        }
        chist[c][kb] = inc - v;    // exclusive over chunks
        if (c == 31) htot[kb] = inc;
      }
    }
  }
  __syncthreads();

  // gbase[k] = #elements with key > k  (suffix sum, one wave, 3 rounds)
  if (t < 64) {
    int carry = 0;
    #pragma unroll
    for (int rd = 0; rd < 3; ++rd) {
      int k = 128 - (rd * 64 + lane);
      int v = (k >= 0) ? htot[k] : 0;
      int inc = v;
      #pragma unroll
      for (int d = 1; d < 64; d <<= 1) {
        int o = __shfl_up(inc, d, 64);
        if (lane >= d) inc += o;
      }
      if (k >= 0) gbase[k] = carry + inc - v;   // exclusive in desc-k order
      carry += __shfl(inc, 63, 64);
    }
  }
  __syncthreads();

  // in-chunk stable prefix via 8-ballot match mask (key in [0,128] -> 8 bits)
  unsigned long long lt = (lane == 0) ? 0ull : (~0ull >> (64 - lane));
  {
    unsigned long long m = ~0ull;
    #pragma unroll
    for (int bit = 0; bit < 8; ++bit) {
      unsigned long long bb = __ballot(((k0 >> bit) & 1) != 0);
      m &= ((k0 >> bit) & 1) ? bb : ~bb;
    }
    int pre0 = __popcll(m & lt);
    int r0 = gbase[k0] + chist[w][k0] + pre0;
    if (r0 < NSEL) { top_m[r0] = t; out_tail[r0] = (float)t; }
  }
  {
    unsigned long long m = ~0ull;
    #pragma unroll
    for (int bit = 0; bit < 8; ++bit) {
      unsigned long long bb = __ballot(((k1 >> bit) & 1) != 0);
      m &= ((k1 >> bit) & 1) ? bb : ~bb;
    }
    int pre1 = __popcll(m & lt);
    int r1 = gbase[k1] + chist[16 + w][k1] + pre1;
    if (r1 < NSEL) { top_m[r1] = t + 1024; out_tail[r1] = (float)(t + 1024); }
  }
}

// ---------------------------------------------------------------------------
// Kernel 4: gather (fused x+y, per-wave, barrier-free). 1024 blocks x 256.
// Wave-private 8KB LDS row buffer; depth-1 register prefetch; nt loads/stores.
// ---------------------------------------------------------------------------
__global__ void __launch_bounds__(256)
gather_kernel(const float* __restrict__ x,
              const float* __restrict__ y,
              const int* __restrict__ top_m,
              float* __restrict__ xs,
              float* __restrict__ ys) {
  __shared__ float rowbuf[4][NN];   // 32KB: one 8KB row per wave
  __shared__ int cols[NSEL];
  int t = threadIdx.x;
  int w = t >> 6, lane = t & 63;
  int blk = blockIdx.x;             // 0..1023
  int b = blk >> 4;
  int iblk = blk & 15;

  cols[t]       = top_m[t];
  cols[t + 256] = top_m[t + 256];
  __syncthreads();                  // the only block barrier

  float* myrow = rowbuf[w];
  int i0 = iblk * 32 + w * 8;       // this wave's 8 rows
  const float* ybase = y + (size_t)b * NN * NN;

  fx4 pr[8];
  {
    int r = cols[i0];
    const fx4* src = (const fx4*)(ybase + (size_t)r * NN);
    #pragma unroll
    for (int j = 0; j < 8; ++j)
      pr[j] = __builtin_nontemporal_load(&src[lane + 64 * j]);
  }

  #pragma unroll
  for (int k = 0; k < 8; ++k) {
    int i = i0 + k;
    {
      fx4* mb = (fx4*)myrow;
      #pragma unroll
      for (int j = 0; j < 8; ++j) mb[lane + 64 * j] = pr[j];
    }
    if (k < 7) {
      int rn = cols[i + 1];
      const fx4* src = (const fx4*)(ybase + (size_t)rn * NN);
      #pragma unroll
      for (int j = 0; j < 8; ++j)
        pr[j] = __builtin_nontemporal_load(&src[lane + 64 * j]);
    }
    {
      int r = cols[i];
      const fx4* xsrc = (const fx4*)(x + ((size_t)b * NN + r) * DD);
      fx4*       xdst = (fx4*)(xs + ((size_t)b * NSEL + i) * DD);
      #pragma unroll
      for (int j = 0; j < 2; ++j) {
        fx4 v = __builtin_nontemporal_load(&xsrc[lane + 64 * j]);
        __builtin_nontemporal_store(v, &xdst[lane + 64 * j]);
      }
    }
    {
      float o[8];
      #pragma unroll
      for (int j = 0; j < 8; ++j) o[j] = myrow[cols[8 * lane + j]];
      fx4* dst = (fx4*)(ys + ((size_t)b * NSEL + i) * DD);
      fx4 o0 = {o[0], o[1], o[2], o[3]};
      fx4 o1 = {o[4], o[5], o[6], o[7]};
      __builtin_nontemporal_store(o0, &dst[2 * lane]);
      __builtin_nontemporal_store(o1, &dst[2 * lane + 1]);
    }
  }
}

// ---------------------------------------------------------------------------
extern "C" void kernel_launch(void* const* d_in, const int* in_sizes, int n_in,
                              void* d_out, int out_size, void* d_ws, size_t ws_size,
                              hipStream_t stream) {
  const float* x    = (const float*)d_in[0];   // (64, 2048, 512)
  const float* y    = (const float*)d_in[1];   // (64, 2048, 2048)
  const float* att  = (const float*)d_in[2];   // (64, 2048)
  const float* aoff = (const float*)d_in[3];   // (64, 2048)

  float* out  = (float*)d_out;
  float* xs   = out;                                    // 64*512*512
  float* ysel = out + (size_t)BB * NSEL * DD;           // 64*512*512
  float* tail = ysel + (size_t)BB * NSEL * NSEL;        // 512 floats

  float* thr   = (float*)d_ws;                          // 128 floats
  int*   key   = (int*)d_ws + 128;                      // 2048 ints
  int*   top_m = (int*)d_ws + 128 + NN;                 // 512 ints

  hipLaunchKernelGGL(thr_kernel, dim3(2 * BB), dim3(64), 0, stream, att, aoff, thr);
  hipLaunchKernelGGL(mkey_kernel, dim3(32), dim3(64), 0, stream, att, aoff, thr, key);
  hipLaunchKernelGGL(topm_kernel, dim3(1), dim3(1024), 0, stream, key, top_m, tail);
  hipLaunchKernelGGL(gather_kernel, dim3(BB * 16), dim3(256), 0, stream,
                     x, y, top_m, xs, ysel);
}